// Round 9
// baseline (42.768 us; speedup 1.0000x reference)
//
#include <hip/hip_runtime.h>

#define FF 7
#define BLOCK 256
#define WAVES_PER_BLOCK (BLOCK / 64)
#define PIX_PER_LANE 4
#define PIX_PER_WAVE (64 * PIX_PER_LANE)        // 256 pixels
#define V4_PER_WAVE (PIX_PER_WAVE * FF / 4)     // 448 float4 = 7168 B
#define NBLOCKS 2048

typedef float vfloat4 __attribute__((ext_vector_type(4)));

// Intra-wave LDS ordering fence. Without __syncthreads, the compiler has no
// obligation to keep cross-lane ds_write -> ds_read pairs ordered or to
// drain lgkmcnt before the dependent read (rule-#18 failure class; round 8
// silently corrupted without this). The "memory" clobber stops IR-level
// reordering; sched_barrier(0) stops the backend scheduler.
#define WAVE_LDS_FENCE() do {                              \
    asm volatile("s_waitcnt lgkmcnt(0)" ::: "memory");     \
    __builtin_amdgcn_sched_barrier(0);                     \
} while (0)

__global__ __launch_bounds__(BLOCK) void fused_scale_matmul_kernel(
    const float* __restrict__ x,   // [npix * 7]
    const float* __restrict__ d,   // [npix]
    const float* __restrict__ W,   // [7 * 7]
    float* __restrict__ out,       // [npix * 7]
    int npix)
{
    // Per-wave private LDS region: redistribution is wave-internal; ordering
    // enforced by explicit fences, no s_barrier anywhere.
    __shared__ vfloat4 lds[WAVES_PER_BLOCK * V4_PER_WAVE];  // 28 KB

    const int tid = threadIdx.x;
    const int lane = tid & 63;
    const int wid = tid >> 6;
    vfloat4* wlds = lds + wid * V4_PER_WAVE;

    // W: uniform address -> scalar (SGPR) loads, broadcast to all lanes.
    float w[FF][FF];
#pragma unroll
    for (int f = 0; f < FF; ++f)
#pragma unroll
        for (int g = 0; g < FF; ++g)
            w[f][g] = W[f * FF + g];

    const int ntiles = npix / PIX_PER_WAVE;                    // 16384
    const int nwaves = NBLOCKS * WAVES_PER_BLOCK;              // 8192
    const int wave0 = blockIdx.x * WAVES_PER_BLOCK + wid;

    const vfloat4* xg = reinterpret_cast<const vfloat4*>(x);
    vfloat4* og = reinterpret_cast<vfloat4*>(out);

    for (int t = wave0; t < ntiles; t += nwaves) {
        const long long tb4 = (long long)t * V4_PER_WAVE;      // float4 units
        const long long tpix = (long long)t * PIX_PER_WAVE;

        // Coalesced loads: each instruction = 64 lanes x 16B contiguous.
        vfloat4 v[FF];
#pragma unroll
        for (int k = 0; k < FF; ++k)
            v[k] = xg[tb4 + k * 64 + lane];
        vfloat4 dv = *reinterpret_cast<const vfloat4*>(d + tpix + lane * PIX_PER_LANE);

        // Wave-local transpose in: linear -> pixel-major.
#pragma unroll
        for (int k = 0; k < FF; ++k)
            wlds[k * 64 + lane] = v[k];
        WAVE_LDS_FENCE();              // RAW: cross-lane writes -> reads

        float xs[PIX_PER_LANE * FF];
        vfloat4* xv = reinterpret_cast<vfloat4*>(xs);
#pragma unroll
        for (int k = 0; k < FF; ++k)
            xv[k] = wlds[lane * FF + k];   // conflict-free (verified r5)
        WAVE_LDS_FENCE();              // WAR: reads done before overwrite

        float dd[PIX_PER_LANE] = {dv.x, dv.y, dv.z, dv.w};
        float ov[PIX_PER_LANE * FF];
#pragma unroll
        for (int p = 0; p < PIX_PER_LANE; ++p) {
#pragma unroll
            for (int g = 0; g < FF; ++g) {
                float acc = 0.0f;
#pragma unroll
                for (int f = 0; f < FF; ++f)
                    acc = fmaf(xs[p * FF + f], w[f][g], acc);
                ov[p * FF + g] = dd[p] * acc;
            }
        }

        // Wave-local transpose out: pixel-major -> linear.
        const vfloat4* os = reinterpret_cast<const vfloat4*>(ov);
#pragma unroll
        for (int k = 0; k < FF; ++k)
            wlds[lane * FF + k] = os[k];
        WAVE_LDS_FENCE();              // RAW: cross-lane writes -> reads

        vfloat4 sv[FF];
#pragma unroll
        for (int k = 0; k < FF; ++k)
            sv[k] = wlds[k * 64 + lane];
        WAVE_LDS_FENCE();              // WAR vs next iteration's stage-in

        // Coalesced nt stores: full 64B lines per instruction, no
        // amplification (verified r6), no L3 allocation for the output.
#pragma unroll
        for (int k = 0; k < FF; ++k)
            __builtin_nontemporal_store(sv[k], og + tb4 + k * 64 + lane);
    }
}

extern "C" void kernel_launch(void* const* d_in, const int* in_sizes, int n_in,
                              void* d_out, int out_size, void* d_ws, size_t ws_size,
                              hipStream_t stream) {
    const float* x = (const float*)d_in[0];
    const float* d = (const float*)d_in[1];
    const float* W = (const float*)d_in[2];
    float* out = (float*)d_out;

    int npix = in_sizes[1];  // H * W = 2048 * 2048

    hipLaunchKernelGGL(fused_scale_matmul_kernel,
                       dim3(NBLOCKS), dim3(BLOCK), 0, stream,
                       x, d, W, out, npix);
}